// Round 4
// baseline (2172.216 us; speedup 1.0000x reference)
//
#include <hip/hip_runtime.h>
#include <cstdint>
#include <cstddef>

// ---------------- problem constants ----------------
#define OUT_DIM    65
#define TREE_STRIDE 66
#define N_NODE     1023
#define N_INTN     511

typedef _Float16 f16;
typedef _Float16 f16x8 __attribute__((ext_vector_type(8)));
typedef float    f32x4 __attribute__((ext_vector_type(4)));

// H: 128 rows x 512 cols f16, row-major with kseg XOR swizzle.
// byte(row,col) = row*1024 + ((kseg ^ (row&15))*16) + (col&7)*2
// A-frag ds_read_b128 at (row=base+l16, kseg=ki*4+quad): banks = ((kseg^l16)&7)*4,
// distinct across 8-lane service groups -> conflict-free.
__device__ __forceinline__ int hseg(int row, int kseg) {
  return row * 512 + (((kseg ^ (row & 15)) << 3));
}
__device__ __forceinline__ int hidx(int row, int col) {
  int kseg = col >> 3, j = col & 7;
  return row * 512 + ((kseg ^ (row & 15)) << 3) + j;
}

// ---------------- fused 4-layer MLP over one 128-row tile ----------------
// Layer0: Kin (64 leaf / 224 internal) -> 512, A gathered from global sources.
// Layers 1,2: 512 -> 512, A-frags from LDS H, B-frags direct from global (L2).
// Out: 512 -> 65 (cols padded to 80), written to tree (or dOut at root).
// No barriers inside any K-loop (H read-only during a layer).
__global__ __launch_bounds__(512, 2) void fused_mlp(
    const float* __restrict__ feats,
    const f16* __restrict__ w0t, const float* __restrict__ b0, int Kin,
    const f16* __restrict__ w1t, const float* __restrict__ b1,
    const f16* __restrict__ w2t, const float* __restrict__ b2,
    const f16* __restrict__ wot, const float* __restrict__ bo,
    f16* __restrict__ tree, float* __restrict__ dOut,
    int lvl, int leaf)
{
  extern __shared__ f16 H[];   // 128*512 f16 = 128 KiB

  const int tid  = threadIdx.x;
  const int wave = tid >> 6;
  const int lane = tid & 63;
  const int quad = lane >> 4;
  const int l16  = lane & 15;
  const int wm   = (wave & 1) * 64;     // row group of this wave
  const int wn   = (wave >> 1) * 128;   // col group of this wave
  const long rowBase = (long)blockIdx.x * 128;

  const f32x4 z = {0.f, 0.f, 0.f, 0.f};

  // ================= layer 0 =================
  {
    f32x4 acc[4][8];
#pragma unroll
    for (int i = 0; i < 4; i++)
#pragma unroll
      for (int j = 0; j < 8; j++) acc[i][j] = z;

    // per-mt source pointers for this lane's A rows
    const float* fp[4];
    const f16*   pp[4];
#pragma unroll
    for (int mt = 0; mt < 4; mt++) {
      long rg = rowBase + wm + mt * 16 + l16;
      if (leaf) {
        fp[mt] = feats + rg * 64;
        pp[mt] = nullptr;
      } else {
        long b = rg >> lvl;
        long i = rg - (b << lvl);
        long node = (1L << lvl) - 1 + i;
        fp[mt] = feats + (b * N_INTN + node) * 64;
        pp[mt] = tree + (b * N_NODE + 2 * node + 1) * TREE_STRIDE;  // [L(65) pad R(65)]
      }
    }

    const int nk0 = Kin >> 5;
    for (int ki = 0; ki < nk0; ki++) {
      f16x8 a[4];
      if (leaf) {
#pragma unroll
        for (int mt = 0; mt < 4; mt++) {
          const float4* p = (const float4*)(fp[mt] + ki * 32 + quad * 8);
          float4 v0 = p[0], v1 = p[1];
          a[mt][0] = (f16)v0.x; a[mt][1] = (f16)v0.y; a[mt][2] = (f16)v0.z; a[mt][3] = (f16)v0.w;
          a[mt][4] = (f16)v1.x; a[mt][5] = (f16)v1.y; a[mt][6] = (f16)v1.z; a[mt][7] = (f16)v1.w;
        }
      } else {
#pragma unroll
        for (int mt = 0; mt < 4; mt++) {
#pragma unroll
          for (int j = 0; j < 8; j++) {
            int c = ki * 32 + quad * 8 + j;
            float v;
            if (c < 64)       v = fp[mt][c];
            else if (c < 194) v = (float)pp[mt][c - 64 + (c >= 129 ? 1 : 0)];
            else              v = 0.f;
            a[mt][j] = (f16)v;
          }
        }
      }
      f16x8 b[8];
#pragma unroll
      for (int nt = 0; nt < 8; nt++) {
        int col = wn + nt * 16 + l16;
        b[nt] = *(const f16x8*)(w0t + (long)col * Kin + ki * 32 + quad * 8);
      }
#pragma unroll
      for (int mt = 0; mt < 4; mt++)
#pragma unroll
        for (int nt = 0; nt < 8; nt++)
          acc[mt][nt] = __builtin_amdgcn_mfma_f32_16x16x32_f16(a[mt], b[nt], acc[mt][nt], 0, 0, 0);
    }

    // write h1 -> H (first touch; no pre-barrier needed)
#pragma unroll
    for (int mt = 0; mt < 4; mt++)
#pragma unroll
      for (int nt = 0; nt < 8; nt++)
#pragma unroll
        for (int r = 0; r < 4; r++) {
          int row = wm + mt * 16 + quad * 4 + r;
          int col = wn + nt * 16 + l16;
          float v = acc[mt][nt][r] + b0[col];
          v = v > 0.f ? v : 0.f;
          H[hidx(row, col)] = (f16)v;
        }
    __syncthreads();
  }

  // ================= mid layers (512 -> 512) =================
  auto midLayer = [&](const f16* __restrict__ Wt, const float* __restrict__ bias) {
    f32x4 acc[4][8];
#pragma unroll
    for (int i = 0; i < 4; i++)
#pragma unroll
      for (int j = 0; j < 8; j++) acc[i][j] = z;

    f16x8 bA[8], bB[8];
    // B-frag loader: direct from global (L2-hot), no LDS staging, no barriers.
#define LOADB(buf, ki)                                                          \
    {                                                                           \
      _Pragma("unroll")                                                         \
      for (int nt = 0; nt < 8; nt++) {                                          \
        int col = wn + nt * 16 + l16;                                           \
        (buf)[nt] = *(const f16x8*)(Wt + (long)col * 512 + (ki) * 32 + quad * 8); \
      }                                                                         \
    }
#define LOADA(a, ki)                                                            \
    {                                                                           \
      _Pragma("unroll")                                                         \
      for (int mt = 0; mt < 4; mt++) {                                          \
        int row = wm + mt * 16 + l16;                                           \
        (a)[mt] = *(const f16x8*)&H[hseg(row, (ki) * 4 + quad)];                \
      }                                                                         \
    }
#define DOMFMA(a, b)                                                            \
    {                                                                           \
      _Pragma("unroll")                                                         \
      for (int mt = 0; mt < 4; mt++)                                            \
        _Pragma("unroll")                                                       \
        for (int nt = 0; nt < 8; nt++)                                          \
          acc[mt][nt] = __builtin_amdgcn_mfma_f32_16x16x32_f16((a)[mt], (b)[nt], acc[mt][nt], 0, 0, 0); \
    }

    LOADB(bA, 0)
    for (int ki = 0; ki < 16; ki += 2) {
      f16x8 a0[4];
      LOADA(a0, ki)
      LOADB(bB, ki + 1)
      DOMFMA(a0, bA)
      f16x8 a1[4];
      LOADA(a1, ki + 1)
      if (ki + 2 < 16) LOADB(bA, ki + 2)
      DOMFMA(a1, bB)
    }

    __syncthreads();   // all waves done READING H
#pragma unroll
    for (int mt = 0; mt < 4; mt++)
#pragma unroll
      for (int nt = 0; nt < 8; nt++)
#pragma unroll
        for (int r = 0; r < 4; r++) {
          int row = wm + mt * 16 + quad * 4 + r;
          int col = wn + nt * 16 + l16;
          float v = acc[mt][nt][r] + bias[col];
          v = v > 0.f ? v : 0.f;
          H[hidx(row, col)] = (f16)v;
        }
    __syncthreads();
#undef LOADB
#undef LOADA
#undef DOMFMA
  };

  midLayer(w1t, b1);
  midLayer(w2t, b2);

  // ================= out layer (512 -> 65, cols padded to 80) =================
  {
    // remap: wave handles rows [wave*16, wave*16+16), cols 0..79 (nt<5)
    f32x4 oacc[5];
#pragma unroll
    for (int i = 0; i < 5; i++) oacc[i] = z;
    const int orow = wave * 16 + l16;

    for (int ki = 0; ki < 16; ki++) {
      f16x8 a = *(const f16x8*)&H[hseg(orow, ki * 4 + quad)];
      f16x8 ob[5];
#pragma unroll
      for (int nt = 0; nt < 5; nt++) {
        int col = nt * 16 + l16;
        ob[nt] = *(const f16x8*)(wot + (long)col * 512 + ki * 32 + quad * 8);
      }
#pragma unroll
      for (int nt = 0; nt < 5; nt++)
        oacc[nt] = __builtin_amdgcn_mfma_f32_16x16x32_f16(a, ob[nt], oacc[nt], 0, 0, 0);
    }

#pragma unroll
    for (int nt = 0; nt < 5; nt++)
#pragma unroll
      for (int r = 0; r < 4; r++) {
        int col = nt * 16 + l16;
        if (col < OUT_DIM) {
          long rg = rowBase + wave * 16 + quad * 4 + r;
          float v = oacc[nt][r] + bo[col];
          long b = rg >> lvl;
          long i = rg - (b << lvl);
          long node = (1L << lvl) - 1 + i;
          if (lvl == 0) {
            if (col == 0) dOut[b] = v;
          } else {
            tree[(b * N_NODE + node) * TREE_STRIDE + col] = (f16)v;
          }
        }
      }
  }
}

// ---------------- weight transpose + cast: Wt[n*Kpad + k] = W[k*N + n] ----------------
__global__ void wcast(const float* __restrict__ W, f16* __restrict__ Wt,
                      int K, int N, int Kpad, int Npad) {
  int idx = blockIdx.x * 256 + threadIdx.x;
  if (idx >= Npad * Kpad) return;
  int n = idx / Kpad;
  int k = idx - n * Kpad;
  float v = (n < N && k < K) ? W[(long)k * N + n] : 0.f;
  Wt[idx] = (f16)v;
}

// ---------------- host orchestration ----------------
extern "C" void kernel_launch(void* const* d_in, const int* in_sizes, int n_in,
                              void* d_out, int out_size, void* d_ws, size_t ws_size,
                              hipStream_t stream) {
  const float* leaf_feats     = (const float*)d_in[0];
  const float* internal_feats = (const float*)d_in[1];
  const float* lw0 = (const float*)d_in[2];
  const float* lb0 = (const float*)d_in[3];
  const float* lw1 = (const float*)d_in[4];
  const float* lb1 = (const float*)d_in[5];
  const float* lw2 = (const float*)d_in[6];
  const float* lb2 = (const float*)d_in[7];
  const float* lwo = (const float*)d_in[8];
  const float* lbo = (const float*)d_in[9];
  const float* iw0 = (const float*)d_in[10];
  const float* ib0 = (const float*)d_in[11];
  const float* iw1 = (const float*)d_in[12];
  const float* ib1 = (const float*)d_in[13];
  const float* iw2 = (const float*)d_in[14];
  const float* ib2 = (const float*)d_in[15];
  const float* iwo = (const float*)d_in[16];
  const float* ibo = (const float*)d_in[17];
  float* dOut = (float*)d_out;

  char* ws = (char*)d_ws;
  size_t off = 0;
  auto alloc = [&](size_t bytes) -> void* {
    void* p = ws + off;
    off += (bytes + 255) & ~(size_t)255;
    return p;
  };

  // weights (fp16, transposed, padded) + tree — ~37 MB total
  f16* lw0t = (f16*)alloc((size_t)512 * 64 * 2);
  f16* lw1t = (f16*)alloc((size_t)512 * 512 * 2);
  f16* lw2t = (f16*)alloc((size_t)512 * 512 * 2);
  f16* lwot = (f16*)alloc((size_t)128 * 512 * 2);
  f16* iw0t = (f16*)alloc((size_t)512 * 224 * 2);
  f16* iw1t = (f16*)alloc((size_t)512 * 512 * 2);
  f16* iw2t = (f16*)alloc((size_t)512 * 512 * 2);
  f16* iwot = (f16*)alloc((size_t)128 * 512 * 2);
  f16* tree = (f16*)alloc((size_t)256 * N_NODE * TREE_STRIDE * 2);

  auto wc = [&](const float* W, f16* Wt, int K, int N, int Kpad, int Npad) {
    int total = Npad * Kpad;
    wcast<<<dim3((total + 255) / 256), dim3(256), 0, stream>>>(W, Wt, K, N, Kpad, Npad);
  };
  wc(lw0, lw0t, 64, 512, 64, 512);
  wc(lw1, lw1t, 512, 512, 512, 512);
  wc(lw2, lw2t, 512, 512, 512, 512);
  wc(lwo, lwot, 512, 65, 512, 128);
  wc(iw0, iw0t, 194, 512, 224, 512);
  wc(iw1, iw1t, 512, 512, 512, 512);
  wc(iw2, iw2t, 512, 512, 512, 512);
  wc(iwo, iwot, 512, 65, 512, 128);

  // allow 128 KiB dynamic LDS (host-side attribute set; graph-capture safe)
  static bool attrSet = false;
  if (!attrSet) {
    hipFuncSetAttribute(reinterpret_cast<const void*>(fused_mlp),
                        hipFuncAttributeMaxDynamicSharedMemorySize, 131072);
    attrSet = true;
  }

  const size_t shmem = 131072;

  // leaf pass: 131072 rows -> nodes 511..1022   (lvl=9 mapping: b=rg>>9, node=511+(rg&511))
  fused_mlp<<<dim3(1024), dim3(512), shmem, stream>>>(
      leaf_feats, lw0t, lb0, 64, lw1t, lb1, lw2t, lb2, lwot, lbo,
      tree, dOut, 9, 1);

  // internal levels bottom-up; l=0 writes dOut
  for (int l = 8; l >= 0; l--) {
    fused_mlp<<<dim3(2 << l), dim3(512), shmem, stream>>>(
        internal_feats, iw0t, ib0, 224, iw1t, ib1, iw2t, ib2, iwot, ibo,
        tree, dOut, l, 0);
  }

  (void)in_sizes; (void)n_in; (void)out_size; (void)ws_size;
}

// Round 5
// 1325.301 us; speedup vs baseline: 1.6390x; 1.6390x over previous
//
#include <hip/hip_runtime.h>
#include <cstdint>
#include <cstddef>

// ---------------- problem constants ----------------
#define OUT_DIM    65
#define TREE_STRIDE 66
#define N_NODE     1023
#define N_INTN     511

typedef _Float16 f16;
typedef _Float16 f16x8 __attribute__((ext_vector_type(8)));
typedef _Float16 f16x4 __attribute__((ext_vector_type(4)));
typedef float    f32x4 __attribute__((ext_vector_type(4)));

// H layout: [row][k] f16, row stride 512, with XOR swizzle on the 16B k-segment:
//   elem(row, k) at  row*512 + ((kseg ^ (row&15))<<3) + (k&7),  kseg = k>>3
// loadA  (ds_read_b128): lanes l16 = 16 rows, v = kseg^l16 distinct -> uniform banks.
// storeH (ds_write_b64): same algebra, 2-way worst case (free, m136).

// ---------------- fused 4-layer MLP over one TR-row tile ----------------
// Wave w owns cols [w*64, w*64+64) (disjoint -> each weight read once per block).
// Mid/hidden layers: A-frags from LDS H, B-frags direct from global (L2-hot).
// H-producing layers use SWAPPED mfma(b,a): lane l16 = H row (mod 16),
// reg r = 4 consecutive output cols -> b64 H writes. No barriers inside K-loops.
template<int TR>
__global__ __launch_bounds__(512, 2) void fused_mlp(
    const float* __restrict__ feats,
    const f16* __restrict__ w0t, const float* __restrict__ b0, int Kin,
    const f16* __restrict__ w1t, const float* __restrict__ b1,
    const f16* __restrict__ w2t, const float* __restrict__ b2,
    const f16* __restrict__ wot, const float* __restrict__ bo,
    f16* __restrict__ tree, float* __restrict__ dOut,
    int lvl, int leaf)
{
  constexpr int MT = TR / 16;
  extern __shared__ f16 H[];   // TR * 512 f16

  const int tid  = threadIdx.x;
  const int wave = tid >> 6;
  const int lane = tid & 63;
  const int quad = lane >> 4;
  const int l16  = lane & 15;
  const int wcb  = wave * 64;               // wave col base
  const long rowBase = (long)blockIdx.x * TR;

  const f32x4 z = {0.f, 0.f, 0.f, 0.f};

  // transposed-epilogue: acc[mt][nt] reg r holds C[row = mt*16+l16][col = wcb+nt*16+quad*4+r]
  auto storeH = [&](f32x4 (&acc)[MT][4], const float* __restrict__ bias) {
#pragma unroll
    for (int mt = 0; mt < MT; mt++) {
#pragma unroll
      for (int nt = 0; nt < 4; nt++) {
        const int c0 = wcb + nt * 16 + quad * 4;
        const float4 bv = *(const float4*)(bias + c0);
        f16x4 hv;
        float v0 = acc[mt][nt][0] + bv.x; hv[0] = (f16)(v0 > 0.f ? v0 : 0.f);
        float v1 = acc[mt][nt][1] + bv.y; hv[1] = (f16)(v1 > 0.f ? v1 : 0.f);
        float v2 = acc[mt][nt][2] + bv.z; hv[2] = (f16)(v2 > 0.f ? v2 : 0.f);
        float v3 = acc[mt][nt][3] + bv.w; hv[3] = (f16)(v3 > 0.f ? v3 : 0.f);
        const int row  = mt * 16 + l16;
        const int kseg = c0 >> 3;
        *(f16x4*)&H[row * 512 + (((kseg ^ l16) << 3)) + (quad & 1) * 4] = hv;
      }
    }
  };

  // ================= layer 0 (Kin -> 512) =================
  {
    f32x4 acc[MT][4];
#pragma unroll
    for (int i = 0; i < MT; i++)
#pragma unroll
      for (int j = 0; j < 4; j++) acc[i][j] = z;

    const float* fp[MT];
    const f16*   pp[MT];
#pragma unroll
    for (int mt = 0; mt < MT; mt++) {
      long rg = rowBase + mt * 16 + l16;
      if (leaf) {
        fp[mt] = feats + rg * 64;
        pp[mt] = nullptr;
      } else {
        long b = rg >> lvl;
        long i = rg - (b << lvl);
        long node = (1L << lvl) - 1 + i;
        fp[mt] = feats + (b * N_INTN + node) * 64;
        pp[mt] = tree + (b * N_NODE + 2 * node + 1) * TREE_STRIDE;  // [L(65)|pad|R(65)]
      }
    }

    const int nk0 = Kin >> 5;
    for (int ki = 0; ki < nk0; ki++) {
      f16x8 a[MT];
      if (leaf) {
#pragma unroll
        for (int mt = 0; mt < MT; mt++) {
          const float4* p = (const float4*)(fp[mt] + ki * 32 + quad * 8);
          float4 u0 = p[0], u1 = p[1];
          a[mt][0] = (f16)u0.x; a[mt][1] = (f16)u0.y; a[mt][2] = (f16)u0.z; a[mt][3] = (f16)u0.w;
          a[mt][4] = (f16)u1.x; a[mt][5] = (f16)u1.y; a[mt][6] = (f16)u1.z; a[mt][7] = (f16)u1.w;
        }
      } else {
#pragma unroll
        for (int mt = 0; mt < MT; mt++) {
#pragma unroll
          for (int j = 0; j < 8; j++) {
            int c = ki * 32 + quad * 8 + j;
            float v;
            if (c < 64)       v = fp[mt][c];
            else if (c < 194) v = (float)pp[mt][c - 64 + (c >= 129 ? 1 : 0)];
            else              v = 0.f;
            a[mt][j] = (f16)v;
          }
        }
      }
      f16x8 b[4];
#pragma unroll
      for (int nt = 0; nt < 4; nt++) {
        int col = wcb + nt * 16 + l16;
        b[nt] = *(const f16x8*)(w0t + (long)col * Kin + ki * 32 + quad * 8);
      }
#pragma unroll
      for (int mt = 0; mt < MT; mt++)
#pragma unroll
        for (int nt = 0; nt < 4; nt++)
          acc[mt][nt] = __builtin_amdgcn_mfma_f32_16x16x32_f16(b[nt], a[mt], acc[mt][nt], 0, 0, 0);
    }
    storeH(acc, b0);
    __syncthreads();
  }

  // ================= mid layers (512 -> 512) =================
  auto midLayer = [&](const f16* __restrict__ Wt, const float* __restrict__ bias) {
    f32x4 acc[MT][4];
#pragma unroll
    for (int i = 0; i < MT; i++)
#pragma unroll
      for (int j = 0; j < 4; j++) acc[i][j] = z;

    f16x8 bc[4], bn[4];
    auto loadB = [&](f16x8 (&bf)[4], int ki) {
#pragma unroll
      for (int nt = 0; nt < 4; nt++) {
        int col = wcb + nt * 16 + l16;
        bf[nt] = *(const f16x8*)(Wt + (long)col * 512 + ki * 32 + quad * 8);
      }
    };
    auto loadA = [&](f16x8 (&af)[MT], int ki) {
#pragma unroll
      for (int mt = 0; mt < MT; mt++) {
        int row = mt * 16 + l16;
        af[mt] = *(const f16x8*)&H[row * 512 + ((((ki * 4 + quad) ^ l16) << 3))];
      }
    };

    loadB(bc, 0);
#pragma unroll
    for (int ki = 0; ki < 16; ki += 2) {
      f16x8 a0[MT];
      loadA(a0, ki);
      loadB(bn, ki + 1);
#pragma unroll
      for (int mt = 0; mt < MT; mt++)
#pragma unroll
        for (int nt = 0; nt < 4; nt++)
          acc[mt][nt] = __builtin_amdgcn_mfma_f32_16x16x32_f16(bc[nt], a0[mt], acc[mt][nt], 0, 0, 0);
      f16x8 a1[MT];
      loadA(a1, ki + 1);
      if (ki + 2 < 16) loadB(bc, ki + 2);
#pragma unroll
      for (int mt = 0; mt < MT; mt++)
#pragma unroll
        for (int nt = 0; nt < 4; nt++)
          acc[mt][nt] = __builtin_amdgcn_mfma_f32_16x16x32_f16(bn[nt], a1[mt], acc[mt][nt], 0, 0, 0);
    }

    __syncthreads();          // all waves done READING H
    storeH(acc, bias);
    __syncthreads();
  };

  midLayer(w1t, b1);
  midLayer(w2t, b2);

  // ================= out layer (512 -> 65, cols padded to 80) =================
  if (wave * 16 < TR) {
    f32x4 oacc[5];
#pragma unroll
    for (int i = 0; i < 5; i++) oacc[i] = z;
    const int orow = wave * 16 + l16;

#pragma unroll
    for (int ki = 0; ki < 16; ki++) {
      f16x8 a = *(const f16x8*)&H[orow * 512 + ((((ki * 4 + quad) ^ l16) << 3))];
      f16x8 ob[5];
#pragma unroll
      for (int nt = 0; nt < 5; nt++) {
        int col = nt * 16 + l16;
        ob[nt] = *(const f16x8*)(wot + (long)col * 512 + ki * 32 + quad * 8);
      }
#pragma unroll
      for (int nt = 0; nt < 5; nt++)
        oacc[nt] = __builtin_amdgcn_mfma_f32_16x16x32_f16(a, ob[nt], oacc[nt], 0, 0, 0);  // normal order
    }

#pragma unroll
    for (int nt = 0; nt < 5; nt++)
#pragma unroll
      for (int r = 0; r < 4; r++) {
        int col = nt * 16 + l16;
        if (col < OUT_DIM) {
          long rg = rowBase + wave * 16 + quad * 4 + r;
          float v = oacc[nt][r] + bo[col];
          long b = rg >> lvl;
          long i = rg - (b << lvl);
          long node = (1L << lvl) - 1 + i;
          if (lvl == 0) {
            if (col == 0) dOut[b] = v;
          } else {
            tree[(b * N_NODE + node) * TREE_STRIDE + col] = (f16)v;
          }
        }
      }
  }
}

// ---------------- merged weight transpose+cast: Wt[n*Kpad+k] = W[k*N+n] ----------------
struct WSeg { const float* W; f16* Wt; int K, N, Kpad, start; };
struct WPack { WSeg s[8]; int total; };

__global__ void wcast_all(WPack p) {
  int idx = blockIdx.x * 256 + threadIdx.x;
  if (idx >= p.total) return;
  int si = 0;
#pragma unroll
  for (int i = 1; i < 8; i++) if (idx >= p.s[i].start) si = i;
  WSeg sg = p.s[si];
  int e = idx - sg.start;
  int n = e / sg.Kpad, k = e - n * sg.Kpad;
  float v = (n < sg.N && k < sg.K) ? sg.W[(long)k * sg.N + n] : 0.f;
  sg.Wt[e] = (f16)v;
}

// ---------------- host orchestration ----------------
extern "C" void kernel_launch(void* const* d_in, const int* in_sizes, int n_in,
                              void* d_out, int out_size, void* d_ws, size_t ws_size,
                              hipStream_t stream) {
  const float* leaf_feats     = (const float*)d_in[0];
  const float* internal_feats = (const float*)d_in[1];
  const float* lw0 = (const float*)d_in[2];
  const float* lb0 = (const float*)d_in[3];
  const float* lw1 = (const float*)d_in[4];
  const float* lb1 = (const float*)d_in[5];
  const float* lw2 = (const float*)d_in[6];
  const float* lb2 = (const float*)d_in[7];
  const float* lwo = (const float*)d_in[8];
  const float* lbo = (const float*)d_in[9];
  const float* iw0 = (const float*)d_in[10];
  const float* ib0 = (const float*)d_in[11];
  const float* iw1 = (const float*)d_in[12];
  const float* ib1 = (const float*)d_in[13];
  const float* iw2 = (const float*)d_in[14];
  const float* ib2 = (const float*)d_in[15];
  const float* iwo = (const float*)d_in[16];
  const float* ibo = (const float*)d_in[17];
  float* dOut = (float*)d_out;

  char* ws = (char*)d_ws;
  size_t off = 0;
  auto alloc = [&](size_t bytes) -> void* {
    void* p = ws + off;
    off += (bytes + 255) & ~(size_t)255;
    return p;
  };

  f16* lw0t = (f16*)alloc((size_t)512 * 64 * 2);
  f16* lw1t = (f16*)alloc((size_t)512 * 512 * 2);
  f16* lw2t = (f16*)alloc((size_t)512 * 512 * 2);
  f16* lwot = (f16*)alloc((size_t)128 * 512 * 2);
  f16* iw0t = (f16*)alloc((size_t)512 * 224 * 2);
  f16* iw1t = (f16*)alloc((size_t)512 * 512 * 2);
  f16* iw2t = (f16*)alloc((size_t)512 * 512 * 2);
  f16* iwot = (f16*)alloc((size_t)128 * 512 * 2);
  f16* tree = (f16*)alloc((size_t)256 * N_NODE * TREE_STRIDE * 2);

  // merged weight prep: one dispatch
  WPack p;
  int cum = 0;
  auto seg = [&](int i, const float* W, f16* Wt, int K, int N, int Kpad, int Npad) {
    p.s[i] = {W, Wt, K, N, Kpad, cum};
    cum += Kpad * Npad;
  };
  seg(0, lw0, lw0t, 64, 512, 64, 512);
  seg(1, lw1, lw1t, 512, 512, 512, 512);
  seg(2, lw2, lw2t, 512, 512, 512, 512);
  seg(3, lwo, lwot, 512, 65, 512, 128);
  seg(4, iw0, iw0t, 194, 512, 224, 512);
  seg(5, iw1, iw1t, 512, 512, 512, 512);
  seg(6, iw2, iw2t, 512, 512, 512, 512);
  seg(7, iwo, iwot, 512, 65, 512, 128);
  p.total = cum;
  wcast_all<<<dim3((cum + 255) / 256), dim3(256), 0, stream>>>(p);

  // allow 128 KiB dynamic LDS for the 128-row variant (same mechanism as round 4, which passed)
  static bool attrSet = false;
  if (!attrSet) {
    hipFuncSetAttribute(reinterpret_cast<const void*>(fused_mlp<128>),
                        hipFuncAttributeMaxDynamicSharedMemorySize, 131072);
    attrSet = true;
  }

  // leaf pass: 131072 rows -> nodes 511..1022
  fused_mlp<128><<<dim3(1024), dim3(512), 131072, stream>>>(
      leaf_feats, lw0t, lb0, 64, lw1t, lb1, lw2t, lb2, lwot, lbo,
      tree, dOut, 9, 1);

  // internal levels bottom-up; l=0 writes dOut
  for (int l = 8; l >= 0; l--) {
    long rows = 256L << l;
    if (l >= 7) {
      fused_mlp<128><<<dim3((unsigned)(rows / 128)), dim3(512), 131072, stream>>>(
          internal_feats, iw0t, ib0, 224, iw1t, ib1, iw2t, ib2, iwot, ibo,
          tree, dOut, l, 0);
    } else {
      fused_mlp<32><<<dim3((unsigned)(rows / 32)), dim3(512), 32768, stream>>>(
          internal_feats, iw0t, ib0, 224, iw1t, ib1, iw2t, ib2, iwot, ibo,
          tree, dOut, l, 0);
    }
  }

  (void)in_sizes; (void)n_in; (void)out_size; (void)ws_size;
}

// Round 6
// 1175.637 us; speedup vs baseline: 1.8477x; 1.1273x over previous
//
#include <hip/hip_runtime.h>
#include <cstdint>
#include <cstddef>
#include <type_traits>

// ---------------- problem constants ----------------
#define OUT_DIM    65
#define TREE_STRIDE 66
#define N_NODE     1023
#define N_INTN     511

typedef _Float16 f16;
typedef _Float16 f16x8 __attribute__((ext_vector_type(8)));
typedef _Float16 f16x4 __attribute__((ext_vector_type(4)));
typedef float    f32x4 __attribute__((ext_vector_type(4)));

#define MFMA(a, b, c) __builtin_amdgcn_mfma_f32_16x16x32_f16((a), (b), (c), 0, 0, 0)

// H layout: [row][k] f16, row stride 512, XOR swizzle on the 16B k-segment:
//   elem(row,k) at row*512 + ((kseg ^ (row&15))<<3) + (k&7), kseg=k>>3
// ds_read_b128 (A-frag) and ds_write_b64 (storeH) both land 2-way worst case (free).

// ---------------- fused 4-layer MLP, TR=64 rows/block, 512 thr ----------------
// Wave w owns cols [w*64, w*64+64): disjoint -> weights read once per block.
// acc[4][4]=64 AGPR; A-frags 16 + B dbuf 32 arch -> no spills (round-5 fix).
__global__ __launch_bounds__(512, 2) void fused_mlp(
    const float* __restrict__ feats,
    const f16* __restrict__ w0t, const float* __restrict__ b0, int Kin,
    const f16* __restrict__ w1t, const float* __restrict__ b1,
    const f16* __restrict__ w2t, const float* __restrict__ b2,
    const f16* __restrict__ wot, const float* __restrict__ bo,
    f16* __restrict__ tree, float* __restrict__ dOut,
    int lvl, int leaf)
{
  extern __shared__ f16 H[];   // 64*512 f16 = 64 KiB

  const int tid  = threadIdx.x;
  const int wave = tid >> 6;
  const int lane = tid & 63;
  const int quad = lane >> 4;
  const int l16  = lane & 15;
  const int wcb  = wave * 64;
  const long rowBase = (long)blockIdx.x * 64;

  const f32x4 z = {0.f, 0.f, 0.f, 0.f};

  // acc[mt][nt] reg r = C[row=mt*16+l16][col=wcb+nt*16+quad*4+r]  (swapped mfma)
  auto storeH = [&](f32x4 (&acc)[4][4], const float* __restrict__ bias) {
#pragma unroll
    for (int mt = 0; mt < 4; mt++) {
#pragma unroll
      for (int nt = 0; nt < 4; nt++) {
        const int c0 = wcb + nt * 16 + quad * 4;
        const float4 bv = *(const float4*)(bias + c0);
        f16x4 hv;
        float v0 = acc[mt][nt][0] + bv.x; hv[0] = (f16)(v0 > 0.f ? v0 : 0.f);
        float v1 = acc[mt][nt][1] + bv.y; hv[1] = (f16)(v1 > 0.f ? v1 : 0.f);
        float v2 = acc[mt][nt][2] + bv.z; hv[2] = (f16)(v2 > 0.f ? v2 : 0.f);
        float v3 = acc[mt][nt][3] + bv.w; hv[3] = (f16)(v3 > 0.f ? v3 : 0.f);
        const int row = mt * 16 + l16;
        *(f16x4*)&H[row * 512 + (((c0 >> 3) ^ l16) << 3) + (quad & 1) * 4] = hv;
      }
    }
  };

  // ================= layer 0 (Kin -> 512) =================
  {
    f32x4 acc[4][4];
#pragma unroll
    for (int i = 0; i < 4; i++)
#pragma unroll
      for (int j = 0; j < 4; j++) acc[i][j] = z;

    const float* fp[4];
    const f16*   pp[4];
#pragma unroll
    for (int mt = 0; mt < 4; mt++) {
      long rg = rowBase + mt * 16 + l16;
      if (leaf) {
        fp[mt] = feats + rg * 64;
        pp[mt] = nullptr;
      } else {
        long b = rg >> lvl;
        long i = rg - (b << lvl);
        long node = (1L << lvl) - 1 + i;
        fp[mt] = feats + (b * N_INTN + node) * 64;
        pp[mt] = tree + (b * N_NODE + 2 * node + 1) * TREE_STRIDE;  // [L(65)|pad|R(65)]
      }
    }

    const int nk0 = Kin >> 5;
    for (int ki = 0; ki < nk0; ki++) {
      f16x8 a[4];
      if (leaf) {
#pragma unroll
        for (int mt = 0; mt < 4; mt++) {
          const float4* p = (const float4*)(fp[mt] + ki * 32 + quad * 8);
          float4 u0 = p[0], u1 = p[1];
          a[mt][0] = (f16)u0.x; a[mt][1] = (f16)u0.y; a[mt][2] = (f16)u0.z; a[mt][3] = (f16)u0.w;
          a[mt][4] = (f16)u1.x; a[mt][5] = (f16)u1.y; a[mt][6] = (f16)u1.z; a[mt][7] = (f16)u1.w;
        }
      } else {
#pragma unroll
        for (int mt = 0; mt < 4; mt++) {
#pragma unroll
          for (int j = 0; j < 8; j++) {
            int c = ki * 32 + quad * 8 + j;
            float v;
            if (c < 64)       v = fp[mt][c];
            else if (c < 194) v = (float)pp[mt][c - 64 + (c >= 129 ? 1 : 0)];
            else              v = 0.f;
            a[mt][j] = (f16)v;
          }
        }
      }
      f16x8 b[4];
#pragma unroll
      for (int nt = 0; nt < 4; nt++) {
        int col = wcb + nt * 16 + l16;
        b[nt] = *(const f16x8*)(w0t + (long)col * Kin + ki * 32 + quad * 8);
      }
#pragma unroll
      for (int mt = 0; mt < 4; mt++)
#pragma unroll
        for (int nt = 0; nt < 4; nt++)
          acc[mt][nt] = MFMA(b[nt], a[mt], acc[mt][nt]);
    }
    storeH(acc, b0);
    __syncthreads();
  }

  // ================= mid layers (512 -> 512) =================
  auto midLayer = [&](const f16* __restrict__ Wt, const float* __restrict__ bias) {
    f32x4 acc[4][4];
#pragma unroll
    for (int i = 0; i < 4; i++)
#pragma unroll
      for (int j = 0; j < 4; j++) acc[i][j] = z;

    f16x8 bc[4], bn[4];
    auto loadB = [&](f16x8 (&bf)[4], int ki) {
#pragma unroll
      for (int nt = 0; nt < 4; nt++) {
        int col = wcb + nt * 16 + l16;
        bf[nt] = *(const f16x8*)(Wt + (long)col * 512 + ki * 32 + quad * 8);
      }
    };
    auto loadA = [&](f16x8 (&af)[4], int ki) {
#pragma unroll
      for (int mt = 0; mt < 4; mt++) {
        int row = mt * 16 + l16;
        af[mt] = *(const f16x8*)&H[row * 512 + ((((ki * 4 + quad) ^ l16) << 3))];
      }
    };

    loadB(bc, 0);
#pragma unroll
    for (int ki = 0; ki < 16; ki += 2) {
      f16x8 a0[4];
      loadA(a0, ki);
      loadB(bn, ki + 1);
#pragma unroll
      for (int mt = 0; mt < 4; mt++)
#pragma unroll
        for (int nt = 0; nt < 4; nt++)
          acc[mt][nt] = MFMA(bc[nt], a0[mt], acc[mt][nt]);
      f16x8 a1[4];
      loadA(a1, ki + 1);
      if (ki + 2 < 16) loadB(bc, ki + 2);
#pragma unroll
      for (int mt = 0; mt < 4; mt++)
#pragma unroll
        for (int nt = 0; nt < 4; nt++)
          acc[mt][nt] = MFMA(bn[nt], a1[mt], acc[mt][nt]);
    }

    __syncthreads();          // all waves done READING H
    storeH(acc, bias);
    __syncthreads();
  };

  midLayer(w1t, b1);
  midLayer(w2t, b2);

  // ================= out layer (512 -> 65, padded 80) =================
  if (wave < 4) {
    f32x4 oacc[5];
#pragma unroll
    for (int i = 0; i < 5; i++) oacc[i] = z;
    const int orow = wave * 16 + l16;

#pragma unroll
    for (int ki = 0; ki < 16; ki++) {
      f16x8 a = *(const f16x8*)&H[orow * 512 + ((((ki * 4 + quad) ^ l16) << 3))];
      f16x8 ob[5];
#pragma unroll
      for (int nt = 0; nt < 5; nt++) {
        int col = nt * 16 + l16;
        ob[nt] = *(const f16x8*)(wot + (long)col * 512 + ki * 32 + quad * 8);
      }
#pragma unroll
      for (int nt = 0; nt < 5; nt++)
        oacc[nt] = MFMA(a, ob[nt], oacc[nt]);   // normal order: row=quad*4+r, col=nt*16+l16
    }

#pragma unroll
    for (int nt = 0; nt < 5; nt++)
#pragma unroll
      for (int r = 0; r < 4; r++) {
        int col = nt * 16 + l16;
        if (col < OUT_DIM) {
          long rg = rowBase + wave * 16 + quad * 4 + r;
          float v = oacc[nt][r] + bo[col];
          long b = rg >> lvl;
          long i = rg - (b << lvl);
          long node = (1L << lvl) - 1 + i;
          tree[(b * N_NODE + node) * TREE_STRIDE + col] = (f16)v;
        }
      }
  }
}

// ---------------- tail: levels 5..0 for one batch element per block ----------------
// 256 blocks x 512 thr. H: 32x512 (swizzled). Child outputs ping-pong in LDS.
// Level-5 children come from tree (level 6); root value -> dOut[b].
__global__ __launch_bounds__(512, 1) void tail_mlp(
    const float* __restrict__ feats,
    const f16* __restrict__ w0t, const float* __restrict__ b0,
    const f16* __restrict__ w1t, const float* __restrict__ b1,
    const f16* __restrict__ w2t, const float* __restrict__ b2,
    const f16* __restrict__ wot, const float* __restrict__ bo,
    const f16* __restrict__ tree, float* __restrict__ dOut)
{
  extern __shared__ f16 S[];
  f16* H = S;                      // 32*512
  f16* childA = S + 32 * 512;      // 32*66
  f16* childB = childA + 32 * 66;

  const int b    = blockIdx.x;
  const int tid  = threadIdx.x;
  const int wave = tid >> 6;
  const int lane = tid & 63;
  const int quad = lane >> 4;
  const int l16  = lane & 15;
  const int wcb  = wave * 64;
  const f32x4 z = {0.f, 0.f, 0.f, 0.f};

  f16* prev = childA;
  f16* cur  = childB;

  auto level = [&](auto MTc, int l) {
    constexpr int MT = decltype(MTc)::value;
    const int M = 1 << l;
    const int nodeBase = M - 1;

    auto storeH = [&](f32x4 (&acc)[MT][4], const float* __restrict__ bias) {
#pragma unroll
      for (int mt = 0; mt < MT; mt++) {
#pragma unroll
        for (int nt = 0; nt < 4; nt++) {
          const int c0 = wcb + nt * 16 + quad * 4;
          const float4 bv = *(const float4*)(bias + c0);
          f16x4 hv;
          float v0 = acc[mt][nt][0] + bv.x; hv[0] = (f16)(v0 > 0.f ? v0 : 0.f);
          float v1 = acc[mt][nt][1] + bv.y; hv[1] = (f16)(v1 > 0.f ? v1 : 0.f);
          float v2 = acc[mt][nt][2] + bv.z; hv[2] = (f16)(v2 > 0.f ? v2 : 0.f);
          float v3 = acc[mt][nt][3] + bv.w; hv[3] = (f16)(v3 > 0.f ? v3 : 0.f);
          const int row = mt * 16 + l16;
          *(f16x4*)&H[row * 512 + (((c0 >> 3) ^ l16) << 3) + (quad & 1) * 4] = hv;
        }
      }
    };

    // ---- layer 0 (K=224) ----
    {
      f32x4 acc[MT][4];
#pragma unroll
      for (int i = 0; i < MT; i++)
#pragma unroll
        for (int j = 0; j < 4; j++) acc[i][j] = z;

      for (int ki = 0; ki < 7; ki++) {
        f16x8 a[MT];
#pragma unroll
        for (int mt = 0; mt < MT; mt++) {
          int row = mt * 16 + l16;
          int rr  = row < M ? row : (M - 1);   // clamp pad rows (not stored later)
          int nn  = nodeBase + rr;
#pragma unroll
          for (int j = 0; j < 8; j++) {
            int c = ki * 32 + quad * 8 + j;
            float v = 0.f;
            if (c < 64) {
              v = feats[((long)b * N_INTN + nn) * 64 + c];
            } else if (c < 194) {
              int cc  = c - 64;                 // 0..129
              int rgt = cc >= 65;
              int col = rgt ? cc - 65 : cc;
              if (l == 5) {
                int ch = 2 * nn + 1 + rgt;      // level-6 nodes
                v = (float)tree[((long)b * N_NODE + ch) * TREE_STRIDE + col];
              } else {
                v = (float)prev[(2 * rr + rgt) * 66 + col];
              }
            }
            a[mt][j] = (f16)v;
          }
        }
        f16x8 bb[4];
#pragma unroll
        for (int nt = 0; nt < 4; nt++) {
          int col = wcb + nt * 16 + l16;
          bb[nt] = *(const f16x8*)(w0t + (long)col * 224 + ki * 32 + quad * 8);
        }
#pragma unroll
        for (int mt = 0; mt < MT; mt++)
#pragma unroll
          for (int nt = 0; nt < 4; nt++)
            acc[mt][nt] = MFMA(bb[nt], a[mt], acc[mt][nt]);
      }
      storeH(acc, b0);   // prior level's H readers finished at end-of-level barrier
      __syncthreads();
    }

    // ---- mid layers ----
    auto mid = [&](const f16* __restrict__ Wt, const float* __restrict__ bias) {
      f32x4 acc[MT][4];
#pragma unroll
      for (int i = 0; i < MT; i++)
#pragma unroll
        for (int j = 0; j < 4; j++) acc[i][j] = z;
#pragma unroll 4
      for (int ki = 0; ki < 16; ki++) {
        f16x8 a[MT];
#pragma unroll
        for (int mt = 0; mt < MT; mt++) {
          int row = mt * 16 + l16;
          a[mt] = *(const f16x8*)&H[row * 512 + ((((ki * 4 + quad) ^ l16) << 3))];
        }
        f16x8 bb[4];
#pragma unroll
        for (int nt = 0; nt < 4; nt++) {
          int col = wcb + nt * 16 + l16;
          bb[nt] = *(const f16x8*)(Wt + (long)col * 512 + ki * 32 + quad * 8);
        }
#pragma unroll
        for (int mt = 0; mt < MT; mt++)
#pragma unroll
          for (int nt = 0; nt < 4; nt++)
            acc[mt][nt] = MFMA(bb[nt], a[mt], acc[mt][nt]);
      }
      __syncthreads();
      storeH(acc, bias);
      __syncthreads();
    };
    mid(w1t, b1);
    mid(w2t, b2);

    // ---- out layer ----
    if (wave < MT) {
      f32x4 oacc[5];
#pragma unroll
      for (int i = 0; i < 5; i++) oacc[i] = z;
      const int orow = wave * 16 + l16;
#pragma unroll 4
      for (int ki = 0; ki < 16; ki++) {
        f16x8 a = *(const f16x8*)&H[orow * 512 + ((((ki * 4 + quad) ^ l16) << 3))];
        f16x8 ob[5];
#pragma unroll
        for (int nt = 0; nt < 5; nt++) {
          int col = nt * 16 + l16;
          ob[nt] = *(const f16x8*)(wot + (long)col * 512 + ki * 32 + quad * 8);
        }
#pragma unroll
        for (int nt = 0; nt < 5; nt++)
          oacc[nt] = MFMA(a, ob[nt], oacc[nt]);
      }
#pragma unroll
      for (int nt = 0; nt < 5; nt++)
#pragma unroll
        for (int r = 0; r < 4; r++) {
          int col = nt * 16 + l16;
          int row = wave * 16 + quad * 4 + r;
          if (col < OUT_DIM && row < M) {
            float v = oacc[nt][r] + bo[col];
            if (l == 0) {
              if (col == 0 && row == 0) dOut[b] = v;
            } else {
              cur[row * 66 + col] = (f16)v;
            }
          }
        }
    }
    __syncthreads();   // cur visible; H readers done -> next level may overwrite
    f16* t = prev; prev = cur; cur = t;
  };

  level(std::integral_constant<int, 2>{}, 5);
  level(std::integral_constant<int, 1>{}, 4);
  level(std::integral_constant<int, 1>{}, 3);
  level(std::integral_constant<int, 1>{}, 2);
  level(std::integral_constant<int, 1>{}, 1);
  level(std::integral_constant<int, 1>{}, 0);
}

// ---------------- merged weight transpose+cast ----------------
struct WSeg { const float* W; f16* Wt; int K, N, Kpad, start; };
struct WPack { WSeg s[8]; int total; };

__global__ void wcast_all(WPack p) {
  int idx = blockIdx.x * 256 + threadIdx.x;
  if (idx >= p.total) return;
  int si = 0;
#pragma unroll
  for (int i = 1; i < 8; i++) if (idx >= p.s[i].start) si = i;
  WSeg sg = p.s[si];
  int e = idx - sg.start;
  int n = e / sg.Kpad, k = e - n * sg.Kpad;
  float v = (n < sg.N && k < sg.K) ? sg.W[(long)k * sg.N + n] : 0.f;
  sg.Wt[e] = (f16)v;
}

// ---------------- host orchestration ----------------
extern "C" void kernel_launch(void* const* d_in, const int* in_sizes, int n_in,
                              void* d_out, int out_size, void* d_ws, size_t ws_size,
                              hipStream_t stream) {
  const float* leaf_feats     = (const float*)d_in[0];
  const float* internal_feats = (const float*)d_in[1];
  const float* lw0 = (const float*)d_in[2];
  const float* lb0 = (const float*)d_in[3];
  const float* lw1 = (const float*)d_in[4];
  const float* lb1 = (const float*)d_in[5];
  const float* lw2 = (const float*)d_in[6];
  const float* lb2 = (const float*)d_in[7];
  const float* lwo = (const float*)d_in[8];
  const float* lbo = (const float*)d_in[9];
  const float* iw0 = (const float*)d_in[10];
  const float* ib0 = (const float*)d_in[11];
  const float* iw1 = (const float*)d_in[12];
  const float* ib1 = (const float*)d_in[13];
  const float* iw2 = (const float*)d_in[14];
  const float* ib2 = (const float*)d_in[15];
  const float* iwo = (const float*)d_in[16];
  const float* ibo = (const float*)d_in[17];
  float* dOut = (float*)d_out;

  char* ws = (char*)d_ws;
  size_t off = 0;
  auto alloc = [&](size_t bytes) -> void* {
    void* p = ws + off;
    off += (bytes + 255) & ~(size_t)255;
    return p;
  };

  f16* lw0t = (f16*)alloc((size_t)512 * 64 * 2);
  f16* lw1t = (f16*)alloc((size_t)512 * 512 * 2);
  f16* lw2t = (f16*)alloc((size_t)512 * 512 * 2);
  f16* lwot = (f16*)alloc((size_t)128 * 512 * 2);
  f16* iw0t = (f16*)alloc((size_t)512 * 224 * 2);
  f16* iw1t = (f16*)alloc((size_t)512 * 512 * 2);
  f16* iw2t = (f16*)alloc((size_t)512 * 512 * 2);
  f16* iwot = (f16*)alloc((size_t)128 * 512 * 2);
  f16* tree = (f16*)alloc((size_t)256 * N_NODE * TREE_STRIDE * 2);

  WPack p;
  int cum = 0;
  auto seg = [&](int i, const float* W, f16* Wt, int K, int N, int Kpad, int Npad) {
    p.s[i] = {W, Wt, K, N, Kpad, cum};
    cum += Kpad * Npad;
  };
  seg(0, lw0, lw0t, 64, 512, 64, 512);
  seg(1, lw1, lw1t, 512, 512, 512, 512);
  seg(2, lw2, lw2t, 512, 512, 512, 512);
  seg(3, lwo, lwot, 512, 65, 512, 128);
  seg(4, iw0, iw0t, 194, 512, 224, 512);
  seg(5, iw1, iw1t, 512, 512, 512, 512);
  seg(6, iw2, iw2t, 512, 512, 512, 512);
  seg(7, iwo, iwot, 512, 65, 512, 128);
  p.total = cum;
  wcast_all<<<dim3((cum + 255) / 256), dim3(256), 0, stream>>>(p);

  static bool attrSet = false;
  if (!attrSet) {
    hipFuncSetAttribute(reinterpret_cast<const void*>(fused_mlp),
                        hipFuncAttributeMaxDynamicSharedMemorySize, 65536);
    hipFuncSetAttribute(reinterpret_cast<const void*>(tail_mlp),
                        hipFuncAttributeMaxDynamicSharedMemorySize, 65536);
    attrSet = true;
  }

  // leaf pass: 131072 rows -> nodes 511..1022
  fused_mlp<<<dim3(2048), dim3(512), 65536, stream>>>(
      leaf_feats, lw0t, lb0, 64, lw1t, lb1, lw2t, lb2, lwot, lbo,
      tree, dOut, 9, 1);

  // big internal levels 8..6
  for (int l = 8; l >= 6; l--) {
    long rows = 256L << l;
    fused_mlp<<<dim3((unsigned)(rows / 64)), dim3(512), 65536, stream>>>(
        internal_feats, iw0t, ib0, 224, iw1t, ib1, iw2t, ib2, iwot, ibo,
        tree, dOut, l, 0);
  }

  // levels 5..0 in one dispatch (one block per batch element)
  const size_t tailShmem = (32 * 512 + 2 * 32 * 66) * sizeof(f16);
  tail_mlp<<<dim3(256), dim3(512), tailShmem, stream>>>(
      internal_feats, iw0t, ib0, iw1t, ib1, iw2t, ib2, iwot, ibo, tree, dOut);

  (void)in_sizes; (void)n_in; (void)out_size; (void)ws_size;
}